// Round 9
// baseline (6523.193 us; speedup 1.0000x reference)
//
#include <hip/hip_runtime.h>

typedef unsigned int u32;
typedef unsigned short u16;
typedef unsigned long long u64;
typedef __attribute__((ext_vector_type(8))) short short8;
typedef __attribute__((ext_vector_type(4))) float f32x4;
typedef __attribute__((ext_vector_type(4))) u32 u32x4;
typedef __attribute__((ext_vector_type(2))) u32 u32x2;

#define SEQ 512
#define BATCH 32
#define DIM 1024
#define NB 64    // persistent blocks in recurrent kernel (16 dims each)

// workspace layout (bytes)
#define OFF_XT    0ull                  // bf16 [16384][1024] Xt (dead after k_gemm)
                                        // -> REUSED: hX history slots 0..511 (32MB)
#define OFF_UBT   33554432ull           // bf16 [4096][1024] U^T (dead after k_gemm)
                                        // -> REUSED: tagged h parity buffers 2x128KB
#define OFF_WG2   41943040ull           // bf16 [64 blk][128 grp][64 lane][8] frag-order W
#define OFF_XPROJ 50331648ull           // bf16 xp2 [512 s][128 reg][64 lane][16 slot]
#define OFF_BIAS  184680448ull          // f32  [4096]

__device__ __forceinline__ float bf2f(u16 u) {
  union { u32 u; float f; } v; v.u = ((u32)u) << 16; return v.f;
}
__device__ __forceinline__ u16 f2bf(float f) {
  union { float f; u32 u; } v; v.f = f;
  u32 r = v.u + 0x7FFFu + ((v.u >> 16) & 1u);
  return (u16)(r >> 16);
}
// tanh(x) = 1 - 2/(1+e^{2x}) : exact identity, __expf-based
__device__ __forceinline__ float tanh_fast(float x) {
  return 1.f - 2.f / (1.f + __expf(2.f * x));
}
__device__ __forceinline__ void gload_lds16(const u16* g, u16* l) {
  __builtin_amdgcn_global_load_lds(
      (const __attribute__((address_space(1))) u32*)g,
      (__attribute__((address_space(3))) u32*)l, 16, 0, 0);
}

// ---------------- init: concat bias ---------------------------------------
__global__ void k_init(float* biasc, const float* bi, const float* bfv,
                       const float* bo, const float* bg) {
  int i = blockIdx.x * 256 + threadIdx.x;
  if (i < 4096) {
    int g = i >> 10, c = i & 1023;
    const float* p = (g == 0) ? bi : (g == 1) ? bfv : (g == 2) ? bo : bg;
    biasc[i] = p[c];
  }
}

// ---------------- zero tagged h parity buffers (AFTER k_gemm; UBT dead) ---
// zeros = (tag 0 | h 0.0) == step-0 state; tag 0 never matches targets >=1
// on the odd parity, so initial garbage there is also covered. 256KB.
__global__ void k_zero(u32x4* p) {     // 64 blocks x 256 x 16B = 256KB
  p[blockIdx.x * 256 + threadIdx.x] = (u32x4){0u, 0u, 0u, 0u};
}

// ---------------- transpose-cast the 8 weight matrices --------------------
// U matrices -> Ubt[e][k] row-major (k_gemm B operand)
// W matrices -> Wg2 MFMA-A-frag order per NB=64 block, m = (d&15)*4 + g:
//   idx = blk*65536 + ((kt*4 + mt)*64 + lane)*8 + (k&7)
//   blk=d>>4, kt=k>>5, mt=m>>4, lane=((k&31)>>3)*16 + (m&15)
__global__ void k_prep_w(const float* Ui, const float* Wi, const float* Uf,
                         const float* Wf, const float* Uo, const float* Wo,
                         const float* Ug, const float* Wg, u16* Ubt, u16* Wg2) {
  __shared__ float tile[64][65];
  int bx = blockIdx.x;
  int mi = bx >> 8;               // matrix 0..7 (Ui,Wi,Uf,Wf,Uo,Wo,Ug,Wg)
  int tt = bx & 255;
  int tr = tt >> 4, tc = tt & 15; // 16x16 grid of 64x64 tiles
  const float* src;
  switch (mi) {
    case 0: src = Ui; break; case 1: src = Wi; break;
    case 2: src = Uf; break; case 3: src = Wf; break;
    case 4: src = Uo; break; case 5: src = Wo; break;
    case 6: src = Ug; break; default: src = Wg; break;
  }
  int g = mi >> 1;
  int d0 = tr * 64, c0 = tc * 64;
  int ty = threadIdx.x >> 6, tx = threadIdx.x & 63;
#pragma unroll
  for (int i = 0; i < 16; ++i) {
    int r = i * 4 + ty;
    tile[r][tx] = src[(size_t)(d0 + r) * 1024 + c0 + tx];
  }
  __syncthreads();
  if (mi & 1) {
#pragma unroll
    for (int i = 0; i < 16; ++i) {
      int cc = i * 4 + ty;
      int d = c0 + cc;                // W column (gate-dim) 0..1023
      int k = d0 + tx;                // W row (input dim) 0..1023
      int blk = d >> 4;
      int m = (d & 15) * 4 + g;
      int mt_ = m >> 4;
      int lane = (((k & 31) >> 3) << 4) + (m & 15);
      size_t idx = (size_t)blk * 65536 +
                   (size_t)((((k >> 5) * 4 + mt_) * 64 + lane)) * 8 + (k & 7);
      Wg2[idx] = f2bf(tile[tx][cc]);
    }
  } else {
#pragma unroll
    for (int i = 0; i < 16; ++i) {
      int cc = i * 4 + ty;
      Ubt[(size_t)((g << 10) + c0 + cc) * 1024 + d0 + tx] = f2bf(tile[tx][cc]);
    }
  }
}

// ---------------- transpose-cast X: Xt[s*32+b][d] = X[b][s][d] ------------
__global__ void k_prep_x(const float* __restrict__ X, u16* __restrict__ Xt) {
  int idx = blockIdx.x * 256 + threadIdx.x;
  int m = idx >> 8, d4 = (idx & 255) << 2;
  int s = m >> 5, b = m & 31;
  const float4* p = (const float4*)(X + (size_t)(b * SEQ + s) * DIM + d4);
  float4 v = *p;
  u16 o[4] = { f2bf(v.x), f2bf(v.y), f2bf(v.z), f2bf(v.w) };
  *(ushort4*)(Xt + (size_t)m * DIM + d4) = *(ushort4*)o;
}

// ---------------- phase 1 GEMM: xp2 = per-lane-slot layout of Xt@U+b ------
// xp2 element for (s, b, col=g*1024+d):
//   addr = (s*128 + d>>3)*1024 + ((d&3)*16 + (b&15))*16 + (b>>4)*8 + ((d&7)>>2)*4 + g
__global__ __launch_bounds__(256) void k_gemm(const u16* __restrict__ Xt,
                                              const u16* __restrict__ Ubt,
                                              const float* __restrict__ biasc,
                                              u16* __restrict__ xp2) {
  __shared__ u16 As[128 * 32];
  __shared__ u16 Bs[128 * 32];
  int tid = threadIdx.x;
  int w = tid >> 6, l = tid & 63;
  int n0 = blockIdx.x * 128, m0 = blockIdx.y * 128;
  int wm = w >> 1, wn = w & 1;
  int lrow = l & 15, lq = l >> 4;
  f32x4 acc[4][4] = {};
  for (int kt = 0; kt < 32; ++kt) {
    int k0 = kt * 32;
    __syncthreads();
#pragma unroll
    for (int is = 0; is < 2; ++is) {
      int c = is * 256 + w * 64 + l;
      int row = c >> 2, kg = c & 3;
      gload_lds16(Xt + (size_t)(m0 + row) * 1024 + k0 + kg * 8, As + c * 8);
      gload_lds16(Ubt + (size_t)(n0 + row) * 1024 + k0 + kg * 8, Bs + c * 8);
    }
    __syncthreads();
    short8 af[4], bfr[4];
#pragma unroll
    for (int mt = 0; mt < 4; ++mt)
      af[mt] = *(const short8*)(As + (wm * 64 + mt * 16 + lrow) * 32 + lq * 8);
#pragma unroll
    for (int nt = 0; nt < 4; ++nt)
      bfr[nt] = *(const short8*)(Bs + (wn * 64 + nt * 16 + lrow) * 32 + lq * 8);
#pragma unroll
    for (int mt = 0; mt < 4; ++mt)
#pragma unroll
      for (int nt = 0; nt < 4; ++nt)
        acc[mt][nt] = __builtin_amdgcn_mfma_f32_16x16x32_bf16(
            af[mt], bfr[nt], acc[mt][nt], 0, 0, 0);
  }
#pragma unroll
  for (int nt = 0; nt < 4; ++nt) {
    int col = n0 + wn * 64 + nt * 16 + lrow;
    float bv = biasc[col];
    int g = col >> 10, d = col & 1023;
    int blkd = d >> 3;
    int slot = ((d & 7) >> 2) * 4 + g;    // rt*4 + g
    int lpart = (d & 3) * 16;             // q*16
#pragma unroll
    for (int mt = 0; mt < 4; ++mt) {
      int rbase = m0 + wm * 64 + mt * 16 + lq * 4;
#pragma unroll
      for (int r = 0; r < 4; ++r) {
        int row = rbase + r;
        int s = row >> 5, b = row & 31;
        xp2[(size_t)(s * 128 + blkd) * 1024 + (lpart + (b & 15)) * 16 +
            (b >> 4) * 8 + slot] = f2bf(acc[mt][nt][r] + bv);
      }
    }
  }
}

// ---------------- phase 2: persistent recurrent kernel --------------------
// R11: tag-synchronized, FLAG-FREE, BARRIER-FREE wave pipelines.
//   NB=64 blocks x 8 waves (512 thr). Wave (mt,nt) computes the 16x16
//   (z-col, batch-half) quadrant; each lane owns ONE cell (4 gates in acc).
//   - W in LDS 128KB (A-frag order), staged once.
//   - h exchanged as TAGGED u32 words ((s+1)<<16 | bf16) in 2 parity
//     buffers; consumer loads straight into registers (dwordx4 sc0 sc1)
//     and accepts iff tag==s.  The load IS the sync: no flags, no acks,
//     no polls, no barriers in the loop.  Producer store is fire&forget.
//   - 3-deep chunk pipeline: 8 chunks/step (4 kt-tiles each), 24 loads in
//     flight max (<=96 VGPRs buffer -> no spill, the R6/R8 killer).
//   - Safety (R5-verified induction, per batch-half): a wave stores tag
//     s+2 only after validating ALL tags s+1 of its half => every same-
//     half wave stored s+1 => consumed tags s => parity overwrite safe.
//   - h history (untagged) stored to per-step slots for k_out.
__global__ __launch_bounds__(512, 2) void k_rec(const u16* __restrict__ Wg2,
                                                const u16* __restrict__ xp2,
                                                u32* tg, u16* hX) {
  __shared__ u16 Ws[65536];          // 128KB A-frag-order W slice
  int tid = threadIdx.x;
  int w = tid >> 6, l = tid & 63;
  int mt = w >> 1, nt = w & 1;
  int blk = blockIdx.x;
  int q = l >> 4, b15 = l & 15;
  // stage W once: 16 linear DMA rounds (wave-uniform base + lane*16B)
#pragma unroll
  for (int it = 0; it < 16; ++it) {
    int c = it * 512 + tid;
    gload_lds16(Wg2 + (size_t)blk * 65536 + c * 8, Ws + c * 8);
  }
  // cell identity: d = blk*16 + mt*4 + q,  b = nt*16 + b15
  int dd = blk * 16 + mt * 4 + q;
  // tagged-store / history offset (R9/R10-verified hfrag formula)
  int toff = (((dd >> 5) * 2 + nt) * 64 + (((dd & 31) >> 3) << 4) + b15) * 8 +
             (dd & 7);
  // xp2 per-thread address pieces
  size_t xbase = ((size_t)(blk * 2 + (mt >> 1))) * 1024 +
                 (q * 16 + b15) * 16 + nt * 8 + (mt & 1) * 4;
  // xq for s=0
  u32x2 xqc, xqn;
  asm volatile("global_load_dwordx2 %0, %1, off" : "=v"(xqc)
               : "v"(xp2 + xbase));
  asm volatile("s_waitcnt vmcnt(0)" ::: "memory");
  __builtin_amdgcn_sched_barrier(0);
  float c_reg = 0.f;
  __syncthreads();                   // Ws staged (only barrier in kernel)

  u32x4 qb[3][8];                    // 3 chunk buffers x 8 quads = 96 VGPRs
#define ISSUE(CB, C)                                                        \
  _Pragma("unroll")                                                         \
  for (int t4 = 0; t4 < 4; ++t4) {                                          \
    const u32* bp = tgr + (((C) * 4 + t4) * 2 + nt) * 512 + l * 8;          \
    asm volatile("global_load_dwordx4 %0, %1, off sc0 sc1"                  \
                 : "=v"(qb[CB][t4 * 2]) : "v"(bp));                         \
    asm volatile("global_load_dwordx4 %0, %1, off offset:16 sc0 sc1"        \
                 : "=v"(qb[CB][t4 * 2 + 1]) : "v"(bp));                     \
  }

  for (int s = 0; s < SEQ; ++s) {
    const u32* tgr = tg + (size_t)(s & 1) * 32768;
    u32 T = (u32)s << 16;
    ISSUE(0, 0) ISSUE(1, 1) ISSUE(2, 2)
    f32x4 a0 = {0.f, 0.f, 0.f, 0.f}, a1 = {0.f, 0.f, 0.f, 0.f};
#pragma unroll
    for (int c = 0; c < 8; ++c) {
      const int cb = c % 3;
      // chunk c landed: leave younger chunks (and nothing else) in flight
      if (c <= 5)      asm volatile("s_waitcnt vmcnt(16)" ::: "memory");
      else if (c == 6) asm volatile("s_waitcnt vmcnt(8)" ::: "memory");
      else             asm volatile("s_waitcnt vmcnt(0)" ::: "memory");
      __builtin_amdgcn_sched_barrier(0);
      // ---- tag check; bulk retry (rare: steady-state skew < load RT) ----
      u32 stale = 0u;
#pragma unroll
      for (int j = 0; j < 8; ++j) {
        u32x4 v = qb[cb][j];
        u32 m = ((v.x ^ T) | (v.y ^ T) | (v.z ^ T) | (v.w ^ T)) & 0xFFFF0000u;
        stale |= m ? (1u << j) : 0u;
      }
      if (__any((int)(stale != 0u))) {
        int guard = 0;
        do {
          if (++guard > 1000000) break;
          __builtin_amdgcn_s_sleep(2);
#pragma unroll
          for (int j = 0; j < 8; ++j)
            if (stale & (1u << j)) {
              const u32* bp = tgr + ((c * 4 + (j >> 1)) * 2 + nt) * 512 + l * 8 +
                              (j & 1) * 4;
              asm volatile("global_load_dwordx4 %0, %1, off sc0 sc1"
                           : "=v"(qb[cb][j]) : "v"(bp));
            }
          asm volatile("s_waitcnt vmcnt(0)" ::: "memory");
          __builtin_amdgcn_sched_barrier(0);
          stale = 0u;
#pragma unroll
          for (int j = 0; j < 8; ++j) {
            u32x4 v = qb[cb][j];
            u32 m = ((v.x ^ T) | (v.y ^ T) | (v.z ^ T) | (v.w ^ T)) &
                    0xFFFF0000u;
            stale |= m ? (1u << j) : 0u;
          }
        } while (__any((int)(stale != 0u)));
      }
      // ---- pack (R6-verified perm) + 4 MFMA, W from LDS -----------------
#pragma unroll
      for (int t4 = 0; t4 < 4; ++t4) {
        int kt = c * 4 + t4;
        u32x4 A = qb[cb][t4 * 2], B = qb[cb][t4 * 2 + 1];
        u32x4 pk = { __builtin_amdgcn_perm(A.y, A.x, 0x05040100u),
                     __builtin_amdgcn_perm(A.w, A.z, 0x05040100u),
                     __builtin_amdgcn_perm(B.y, B.x, 0x05040100u),
                     __builtin_amdgcn_perm(B.w, B.z, 0x05040100u) };
        short8 bfr = __builtin_bit_cast(short8, pk);
        short8 wfr = *(const short8*)(Ws + (kt * 4 + mt) * 512 + l * 8);
        if (kt & 1)
          a1 = __builtin_amdgcn_mfma_f32_16x16x32_bf16(wfr, bfr, a1, 0, 0, 0);
        else
          a0 = __builtin_amdgcn_mfma_f32_16x16x32_bf16(wfr, bfr, a0, 0, 0, 0);
      }
      // issue chunk c+3 into the buffer just consumed
      if (c <= 4) { ISSUE(cb, c + 3) }
    }
    f32x4 z4 = a0 + a1;

    // ---- gates fully in registers: z4 = {zi,zf,zo,zg} of this cell -------
    union { u32x2 v; u16 a[4]; } xq;
    xq.v = xqc;
    float zi = z4[0] + bf2f(xq.a[0]);
    float zf = z4[1] + bf2f(xq.a[1]);
    float zo = z4[2] + bf2f(xq.a[2]);
    float zg = z4[3] + bf2f(xq.a[3]);
    float ig = 1.f / (1.f + __expf(-zi));
    float fg = 1.f / (1.f + __expf(-zf));
    float og = 1.f / (1.f + __expf(-zo));
    float gg = tanh_fast(zg);
    c_reg = 1.f / (1.f + __expf(-(fg * c_reg + ig * gg)));  // nonstandard cell
    float h = tanh_fast(c_reg) * og;
    u16 hb = f2bf(h);

    // ---- fire-and-forget stores: tagged (sync) + history (for k_out) -----
    __hip_atomic_store(tg + (size_t)((s + 1) & 1) * 32768 + toff,
                       ((u32)(s + 1) << 16) | (u32)hb,
                       __ATOMIC_RELAXED, __HIP_MEMORY_SCOPE_AGENT);
    __builtin_nontemporal_store(hb, hX + (size_t)s * 32768 + toff);
    // xq prefetch for s+1 (oldest entries of next step's vmcnt window)
    {
      int sp = (s + 1 < SEQ) ? s + 1 : s;
      asm volatile("global_load_dwordx2 %0, %1, off" : "=v"(xqn)
                   : "v"(xp2 + (size_t)sp * 131072 + xbase));
    }
    xqc = xqn;
  }
#undef ISSUE
}

// ---------------- phase 3: relayout h history -> out (f32) ----------------
__global__ void k_out(const u16* __restrict__ hx, float* __restrict__ out) {
  int t = blockIdx.x * 256 + threadIdx.x;    // 2,097,152 threads, 8 elems each
  int d0 = (t & 127) << 3;
  int rem = t >> 7;
  int s = rem & 511, b = rem >> 9;
  int kt = d0 >> 5, jg = (d0 & 31) >> 3, ct = b >> 4;
  const u16* src = hx + (size_t)s * 32768 +
                   (size_t)(((kt * 2 + ct) * 64 + jg * 16 + (b & 15)) * 8);
  ushort4 v0 = *(const ushort4*)src;
  ushort4 v1 = *(const ushort4*)(src + 4);
  float4 o0 = { bf2f(v0.x), bf2f(v0.y), bf2f(v0.z), bf2f(v0.w) };
  float4 o1 = { bf2f(v1.x), bf2f(v1.y), bf2f(v1.z), bf2f(v1.w) };
  float* dst = out + (size_t)(b * SEQ + s) * DIM + d0;
  *(float4*)dst = o0;
  *(float4*)(dst + 4) = o1;
}

// ---------------------------------------------------------------------------
extern "C" void kernel_launch(void* const* d_in, const int* in_sizes, int n_in,
                              void* d_out, int out_size, void* d_ws,
                              size_t ws_size, hipStream_t stream) {
  const float* X   = (const float*)d_in[0];
  const float* Ui  = (const float*)d_in[1];
  const float* Wi  = (const float*)d_in[2];
  const float* Uf  = (const float*)d_in[3];
  const float* Wf  = (const float*)d_in[4];
  const float* Uo  = (const float*)d_in[5];
  const float* Wo  = (const float*)d_in[6];
  const float* Ug  = (const float*)d_in[7];
  const float* Wg  = (const float*)d_in[8];
  const float* bi  = (const float*)d_in[9];
  const float* bfv = (const float*)d_in[10];
  const float* bo  = (const float*)d_in[11];
  const float* bg  = (const float*)d_in[12];
  char* ws = (char*)d_ws;
  u16* Xt      = (u16*)(ws + OFF_XT);      // Xt for gemm; then hX history
  u16* hX      = (u16*)(ws + OFF_XT);
  u16* Ubt     = (u16*)(ws + OFF_UBT);     // U^T for gemm; then tagged parity
  u32* tg      = (u32*)(ws + OFF_UBT);
  u16* Wg2     = (u16*)(ws + OFF_WG2);
  u16* xp2     = (u16*)(ws + OFF_XPROJ);
  float* biasc = (float*)(ws + OFF_BIAS);
  float* out   = (float*)d_out;

  k_init<<<16, 256, 0, stream>>>(biasc, bi, bfv, bo, bg);
  k_prep_w<<<2048, 256, 0, stream>>>(Ui, Wi, Uf, Wf, Uo, Wo, Ug, Wg, Ubt, Wg2);
  k_prep_x<<<16384, 256, 0, stream>>>(X, Xt);
  k_gemm<<<dim3(32, 128), 256, 0, stream>>>(Xt, Ubt, biasc, xp2);
  k_zero<<<64, 256, 0, stream>>>((u32x4*)tg);   // after gemm: Ubt dead
  k_rec<<<NB, 512, 0, stream>>>(Wg2, xp2, tg, hX);
  k_out<<<8192, 256, 0, stream>>>(hX, out);
}

// Round 10
// 1788.927 us; speedup vs baseline: 3.6464x; 3.6464x over previous
//
#include <hip/hip_runtime.h>

typedef unsigned int u32;
typedef unsigned short u16;
typedef unsigned long long u64;
typedef __attribute__((ext_vector_type(8))) short short8;
typedef __attribute__((ext_vector_type(4))) float f32x4;
typedef __attribute__((ext_vector_type(4))) u32 u32x4;

#define SEQ 512
#define BATCH 32
#define DIM 1024
#define NB 128   // persistent blocks in recurrent kernel

// workspace layout (bytes)
#define OFF_XT    0ull                  // bf16 [16384][1024] Xt (dead after k_gemm)
                                        // -> REUSED: h slots s=0..511, 64KB each (32MB)
#define OFF_UBT   33554432ull           // bf16 [4096][1024] U^T (dead after k_gemm)
                                        // -> REUSED: h slot "-1" = zeros (64KB)
#define OFF_WG2   41943040ull           // bf16 [128 blk][64 grp][64 lane][8] frag-order W
#define OFF_XPROJ 50331648ull           // bf16 xp2 [512 s][128 blk][4 g][8 d'][32 b]
#define OFF_BIAS  184680448ull          // f32  [4096]
#define OFF_SYNC  184696832ull          // u32 flags[128 blk][32] (128B-padded)

__device__ __forceinline__ float bf2f(u16 u) {
  union { u32 u; float f; } v; v.u = ((u32)u) << 16; return v.f;
}
__device__ __forceinline__ u16 f2bf(float f) {
  union { float f; u32 u; } v; v.f = f;
  u32 r = v.u + 0x7FFFu + ((v.u >> 16) & 1u);
  return (u16)(r >> 16);
}
// tanh(x) = 1 - 2/(1+e^{2x}) : exact identity, __expf-based
__device__ __forceinline__ float tanh_fast(float x) {
  return 1.f - 2.f / (1.f + __expf(2.f * x));
}
__device__ __forceinline__ void gload_lds16(const u16* g, u16* l) {
  __builtin_amdgcn_global_load_lds(
      (const __attribute__((address_space(1))) u32*)g,
      (__attribute__((address_space(3))) u32*)l, 16, 0, 0);
}
// LLC-coherent LDS-DMA: aux=17 = SC0|SC1 -> bypass L1+L2, read at LLC
__device__ __forceinline__ void gload_lds16_coh(const u16* g, u16* l) {
  __builtin_amdgcn_global_load_lds(
      (const __attribute__((address_space(1))) u32*)g,
      (__attribute__((address_space(3))) u32*)l, 16, 0, 17);
}

// ---------------- init: concat bias + zero flags --------------------------
__global__ void k_init(float* biasc, u32* sync, const float* bi,
                       const float* bfv, const float* bo, const float* bg) {
  int i = blockIdx.x * 256 + threadIdx.x;
  if (i < 4096) {
    int g = i >> 10, c = i & 1023;
    const float* p = (g == 0) ? bi : (g == 1) ? bfv : (g == 2) ? bo : bg;
    biasc[i] = p[c];
  } else if (i < 8192) {
    sync[i - 4096] = 0u;
  }
}

// ---------------- zero h slot -1 (UBT region; runs AFTER k_gemm) ----------
__global__ void k_zero(u32x4* p) {     // 16 blocks x 256 x 16B = 64KB
  p[blockIdx.x * 256 + threadIdx.x] = (u32x4){0u, 0u, 0u, 0u};
}

// ---------------- transpose-cast the 8 weight matrices --------------------
// U matrices -> Ubt[e][k] row-major (k_gemm B operand)
// W matrices -> Wg2 MFMA-A-frag order per block, gate-dims reordered m=d'*4+g:
//   idx = blk*32768 + ((kt*2+rt)*64 + lane)*8 + j
//   kt=k>>5, rt=(c&7)>>2, lane=((k&31)>>3)*16 + (c&3)*4 + g, j=k&7
// (R10-verified layout)
__global__ void k_prep_w(const float* Ui, const float* Wi, const float* Uf,
                         const float* Wf, const float* Uo, const float* Wo,
                         const float* Ug, const float* Wg, u16* Ubt, u16* Wg2) {
  __shared__ float tile[64][65];
  int bx = blockIdx.x;
  int mi = bx >> 8;               // matrix 0..7 (Ui,Wi,Uf,Wf,Uo,Wo,Ug,Wg)
  int tt = bx & 255;
  int tr = tt >> 4, tc = tt & 15; // 16x16 grid of 64x64 tiles
  const float* src;
  switch (mi) {
    case 0: src = Ui; break; case 1: src = Wi; break;
    case 2: src = Uf; break; case 3: src = Wf; break;
    case 4: src = Uo; break; case 5: src = Wo; break;
    case 6: src = Ug; break; default: src = Wg; break;
  }
  int g = mi >> 1;
  int d0 = tr * 64, c0 = tc * 64;
  int ty = threadIdx.x >> 6, tx = threadIdx.x & 63;
#pragma unroll
  for (int i = 0; i < 16; ++i) {
    int r = i * 4 + ty;
    tile[r][tx] = src[(size_t)(d0 + r) * 1024 + c0 + tx];
  }
  __syncthreads();
  if (mi & 1) {
#pragma unroll
    for (int i = 0; i < 16; ++i) {
      int cc = i * 4 + ty;
      int c_full = c0 + cc;           // W column (gate-dim) 0..1023
      int k = d0 + tx;                // W row (input dim) 0..1023
      int blk = c_full >> 3;
      int lane = (((k & 31) >> 3) << 4) + ((c_full & 3) << 2) + g;
      size_t idx = (size_t)blk * 32768 +
                   (size_t)(((k >> 5) * 2 + ((c_full & 7) >> 2)) * 64 + lane) * 8 +
                   (k & 7);
      Wg2[idx] = f2bf(tile[tx][cc]);
    }
  } else {
#pragma unroll
    for (int i = 0; i < 16; ++i) {
      int cc = i * 4 + ty;
      Ubt[(size_t)((g << 10) + c0 + cc) * 1024 + d0 + tx] = f2bf(tile[tx][cc]);
    }
  }
}

// ---------------- transpose-cast X: Xt[s*32+b][d] = X[b][s][d] ------------
__global__ void k_prep_x(const float* __restrict__ X, u16* __restrict__ Xt) {
  int idx = blockIdx.x * 256 + threadIdx.x;
  int m = idx >> 8, d4 = (idx & 255) << 2;
  int s = m >> 5, b = m & 31;
  const float4* p = (const float4*)(X + (size_t)(b * SEQ + s) * DIM + d4);
  float4 v = *p;
  u16 o[4] = { f2bf(v.x), f2bf(v.y), f2bf(v.z), f2bf(v.w) };
  *(ushort4*)(Xt + (size_t)m * DIM + d4) = *(ushort4*)o;
}

// ---------------- phase 1 GEMM: xp2 = Xt@U+b, LDS-coalesced epilogue ------
// xp2 layout: [s][blkd=d>>3][g][d'=d&7][b]  (2KB contiguous per (s,blkd)).
// Epilogue stages the 128x128 C-tile in cbuf LDS then stores dwordx4 rows
// (fixes R10's scattered 2-byte epilogue stores).
__global__ __launch_bounds__(256) void k_gemm(const u16* __restrict__ Xt,
                                              const u16* __restrict__ Ubt,
                                              const float* __restrict__ biasc,
                                              u16* __restrict__ xp2) {
  __shared__ u16 As[128 * 32];
  __shared__ u16 Bs[128 * 32];
  __shared__ u16 cbuf[4][16][8][32];   // 32KB [s-local][blk16][d'][b]
  int tid = threadIdx.x;
  int w = tid >> 6, l = tid & 63;
  int n0 = blockIdx.x * 128, m0 = blockIdx.y * 128;
  int wm = w >> 1, wn = w & 1;
  int lrow = l & 15, lq = l >> 4;
  f32x4 acc[4][4] = {};
  for (int kt = 0; kt < 32; ++kt) {
    int k0 = kt * 32;
    __syncthreads();
#pragma unroll
    for (int is = 0; is < 2; ++is) {
      int c = is * 256 + w * 64 + l;
      int row = c >> 2, kg = c & 3;
      gload_lds16(Xt + (size_t)(m0 + row) * 1024 + k0 + kg * 8, As + c * 8);
      gload_lds16(Ubt + (size_t)(n0 + row) * 1024 + k0 + kg * 8, Bs + c * 8);
    }
    __syncthreads();
    short8 af[4], bfr[4];
#pragma unroll
    for (int mt = 0; mt < 4; ++mt)
      af[mt] = *(const short8*)(As + (wm * 64 + mt * 16 + lrow) * 32 + lq * 8);
#pragma unroll
    for (int nt = 0; nt < 4; ++nt)
      bfr[nt] = *(const short8*)(Bs + (wn * 64 + nt * 16 + lrow) * 32 + lq * 8);
#pragma unroll
    for (int mt = 0; mt < 4; ++mt)
#pragma unroll
      for (int nt = 0; nt < 4; ++nt)
        acc[mt][nt] = __builtin_amdgcn_mfma_f32_16x16x32_bf16(
            af[mt], bfr[nt], acc[mt][nt], 0, 0, 0);
  }
  // ---- epilogue: bias + cast into cbuf (scattered LDS, cheap) ------------
#pragma unroll
  for (int nt = 0; nt < 4; ++nt) {
    int lc = wn * 64 + nt * 16 + lrow;       // local col 0..127
    float bv = biasc[n0 + lc];
#pragma unroll
    for (int mt = 0; mt < 4; ++mt) {
#pragma unroll
      for (int r = 0; r < 4; ++r) {
        int lr = wm * 64 + mt * 16 + lq * 4 + r;   // local row 0..127
        cbuf[lr >> 5][lc >> 3][lrow & 7][lr & 31] = f2bf(acc[mt][nt][r] + bv);
      }
    }
  }
  __syncthreads();
  // ---- coalesced store: 2048 x 16B units --------------------------------
  int s0 = m0 >> 5, blkd0 = (n0 & 1023) >> 3, gb = (n0 >> 10) * 256;
  const u16* cb = &cbuf[0][0][0][0];
#pragma unroll
  for (int i = 0; i < 8; ++i) {
    int u = i * 256 + tid;
    int r_ = u >> 5, w_ = u & 31;            // r_ = ds*16+blk16
    u32x4 v = *(const u32x4*)(cb + u * 8);
    *(u32x4*)(xp2 + (size_t)((s0 + (r_ >> 4)) * 128 + blkd0 + (r_ & 15)) * 1024 +
              gb + w_ * 8) = v;
  }
}

// ---------------- phase 2: persistent recurrent kernel (4 waves / block) --
// R12 = R10's verified structure (1649us) with ONE change: the per-thread
// xq global load (HBM latency, sat in the syncthreads vmcnt chain) is
// replaced by the R4-proven XPs LDS-DMA parity staging (2KB/step, issued
// after the flag, drained for free by the next step's vmcnt(8)).
//   per step: poll -> 16 coherent DMA rounds -> vmcnt(8)+bar -> MFMA kt0-15
//   -> vmcnt(0)+bar -> MFMA kt16-31 -> in-reg gates (xp from XPs LDS)
//   -> h-store -> syncthreads (ack) -> flag -> XPs(s+1) prefetch.
__global__ __launch_bounds__(256, 1) void k_rec(const u16* __restrict__ Wg2,
                                                const u16* __restrict__ xp2,
                                                u16* hX, const u16* __restrict__ h0,
                                                u32* sync) {
  __shared__ u16 Hs[32768];          // 64KB B-frag-order h(s-1), re-staged
  __shared__ u16 XPs[2][1024];       // 2x2KB xp slice [g][d'][b], dbuf
  int tid = threadIdx.x;
  int w = tid >> 6, l = tid & 63;
  int mt = w >> 1, nt = w & 1;
  int blk = blockIdx.x;
  int q = l >> 4, b15 = l & 15;

  // ---- stage W into registers (A-frag tiles kt*2+mt), static unroll ------
  short8 wf[32];
#pragma unroll
  for (int kt = 0; kt < 32; ++kt)
    wf[kt] = *(const short8*)(Wg2 + (size_t)blk * 32768 + (kt * 2 + mt) * 512 +
                              l * 8);
  // XPs(0) prefetch (2KB, tid<128)
  if (tid < 128)
    gload_lds16(xp2 + (size_t)blk * 1024 + tid * 8, XPs[0] + tid * 8);
  asm volatile("s_waitcnt vmcnt(0)" ::: "memory");
  __builtin_amdgcn_sched_barrier(0);

  // producer h-store offset for cell (d=blk*8+mt*4+q, b=nt*16+b15)
  int hoff = (((blk >> 2) * 2 + nt) * 64 + (blk & 3) * 16 + b15) * 8 + mt * 4 + q;
  // XPs read offset (g stride 256): [g][d'=mt*4+q][b=nt*16+b15]
  int xoff = (mt * 4 + q) * 32 + nt * 16 + b15;
  float c_reg = 0.f;
  __syncthreads();

  for (int s = 0; s < SEQ; ++s) {
    // ---- poll all 128 flags >= s (lane covers flags l, l+64) -------------
    {
      u32 tgt = (u32)s;
      int guard = 0;
      for (;;) {
        u32 a = __hip_atomic_load(sync + l * 32, __ATOMIC_RELAXED,
                                  __HIP_MEMORY_SCOPE_AGENT);
        u32 b = __hip_atomic_load(sync + (64 + l) * 32, __ATOMIC_RELAXED,
                                  __HIP_MEMORY_SCOPE_AGENT);
        if (a >= tgt && b >= tgt) break;
        __builtin_amdgcn_s_sleep(1);
        if (++guard > 1000000) break;    // fail-fast anti-hang bailout
      }
    }
    asm volatile("" ::: "memory");
    __builtin_amdgcn_sched_barrier(0);

    const u16* hs = (s == 0) ? h0 : (hX + (size_t)(s - 1) * 32768);
    // ---- 16 coherent DMA rounds (cooperative): round it = tiles it*4+w ---
#pragma unroll
    for (int it = 0; it < 16; ++it)
      gload_lds16_coh(hs + (it * 256 + tid) * 8, Hs + (it * 256 + tid) * 8);

    f32x4 a0 = {0.f, 0.f, 0.f, 0.f}, a1 = {0.f, 0.f, 0.f, 0.f};
    // rounds 0-7 done -> tiles 0-31 staged (8 younger rounds outstanding)
    asm volatile("s_waitcnt vmcnt(8)" ::: "memory");
    __builtin_amdgcn_sched_barrier(0);
    __builtin_amdgcn_s_barrier();
    __builtin_amdgcn_sched_barrier(0);
#pragma unroll
    for (int kt = 0; kt < 16; kt += 2) {
      short8 b0 = *(const short8*)(Hs + (kt * 2 + nt) * 512 + l * 8);
      short8 b1 = *(const short8*)(Hs + ((kt + 1) * 2 + nt) * 512 + l * 8);
      a0 = __builtin_amdgcn_mfma_f32_16x16x32_bf16(wf[kt], b0, a0, 0, 0, 0);
      a1 = __builtin_amdgcn_mfma_f32_16x16x32_bf16(wf[kt + 1], b1, a1, 0, 0, 0);
    }
    // all 16 rounds done
    asm volatile("s_waitcnt vmcnt(0)" ::: "memory");
    __builtin_amdgcn_sched_barrier(0);
    __builtin_amdgcn_s_barrier();
    __builtin_amdgcn_sched_barrier(0);
#pragma unroll
    for (int kt = 16; kt < 32; kt += 2) {
      short8 b0 = *(const short8*)(Hs + (kt * 2 + nt) * 512 + l * 8);
      short8 b1 = *(const short8*)(Hs + ((kt + 1) * 2 + nt) * 512 + l * 8);
      a0 = __builtin_amdgcn_mfma_f32_16x16x32_bf16(wf[kt], b0, a0, 0, 0, 0);
      a1 = __builtin_amdgcn_mfma_f32_16x16x32_bf16(wf[kt + 1], b1, a1, 0, 0, 0);
    }
    f32x4 z4 = a0 + a1;

    // ---- gates fully in registers: z4 = {zi,zf,zo,zg} of this cell -------
    const u16* xp = XPs[s & 1];
    float zi = z4[0] + bf2f(xp[xoff]);
    float zf = z4[1] + bf2f(xp[256 + xoff]);
    float zo = z4[2] + bf2f(xp[512 + xoff]);
    float zg = z4[3] + bf2f(xp[768 + xoff]);
    float ig = 1.f / (1.f + __expf(-zi));
    float fg = 1.f / (1.f + __expf(-zf));
    float og = 1.f / (1.f + __expf(-zo));
    float gg = tanh_fast(zg);
    c_reg = 1.f / (1.f + __expf(-(fg * c_reg + ig * gg)));  // nonstandard cell
    float h = tanh_fast(c_reg) * og;

    // ---- 1 fire-and-forget h-store, drain via syncthreads, flag ----------
    __hip_atomic_store(hX + (size_t)s * 32768 + hoff, f2bf(h),
                       __ATOMIC_RELAXED, __HIP_MEMORY_SCOPE_AGENT);
    __syncthreads();                 // vmcnt(0)+barrier: all h stores acked
    if (tid == 0)
      __hip_atomic_store(sync + blk * 32, (u32)(s + 1), __ATOMIC_RELAXED,
                         __HIP_MEMORY_SCOPE_AGENT);
    // XPs(s+1) prefetch: issued after the flag, flies through the next
    // poll; drained for free by the next step's vmcnt(8).
    {
      int sp = (s + 1 < SEQ) ? s + 1 : s;
      if (tid < 128)
        gload_lds16(xp2 + ((size_t)sp * 128 + blk) * 1024 + tid * 8,
                    XPs[(s + 1) & 1] + tid * 8);
    }
  }
}

// ---------------- phase 3: relayout h history -> out (f32) ----------------
__global__ void k_out(const u16* __restrict__ hx, float* __restrict__ out) {
  int t = blockIdx.x * 256 + threadIdx.x;    // 2,097,152 threads, 8 elems each
  int d0 = (t & 127) << 3;
  int rem = t >> 7;
  int s = rem & 511, b = rem >> 9;
  int kt = d0 >> 5, jg = (d0 & 31) >> 3, ct = b >> 4;
  const u16* src = hx + (size_t)s * 32768 +
                   (size_t)(((kt * 2 + ct) * 64 + jg * 16 + (b & 15)) * 8);
  ushort4 v0 = *(const ushort4*)src;
  ushort4 v1 = *(const ushort4*)(src + 4);
  float4 o0 = { bf2f(v0.x), bf2f(v0.y), bf2f(v0.z), bf2f(v0.w) };
  float4 o1 = { bf2f(v1.x), bf2f(v1.y), bf2f(v1.z), bf2f(v1.w) };
  float* dst = out + (size_t)(b * SEQ + s) * DIM + d0;
  *(float4*)dst = o0;
  *(float4*)(dst + 4) = o1;
}

// ---------------------------------------------------------------------------
extern "C" void kernel_launch(void* const* d_in, const int* in_sizes, int n_in,
                              void* d_out, int out_size, void* d_ws,
                              size_t ws_size, hipStream_t stream) {
  const float* X   = (const float*)d_in[0];
  const float* Ui  = (const float*)d_in[1];
  const float* Wi  = (const float*)d_in[2];
  const float* Uf  = (const float*)d_in[3];
  const float* Wf  = (const float*)d_in[4];
  const float* Uo  = (const float*)d_in[5];
  const float* Wo  = (const float*)d_in[6];
  const float* Ug  = (const float*)d_in[7];
  const float* Wg  = (const float*)d_in[8];
  const float* bi  = (const float*)d_in[9];
  const float* bfv = (const float*)d_in[10];
  const float* bo  = (const float*)d_in[11];
  const float* bg  = (const float*)d_in[12];
  char* ws = (char*)d_ws;
  u16* Xt      = (u16*)(ws + OFF_XT);      // Xt for gemm; then h slots 0..511
  u16* Ubt     = (u16*)(ws + OFF_UBT);     // U^T for gemm; then h slot -1 (zeros)
  u16* Wg2     = (u16*)(ws + OFF_WG2);
  u16* xp2     = (u16*)(ws + OFF_XPROJ);
  float* biasc = (float*)(ws + OFF_BIAS);
  u32* sync    = (u32*)(ws + OFF_SYNC);
  float* out   = (float*)d_out;

  k_init<<<32, 256, 0, stream>>>(biasc, sync, bi, bfv, bo, bg);
  k_prep_w<<<2048, 256, 0, stream>>>(Ui, Wi, Uf, Wf, Uo, Wo, Ug, Wg, Ubt, Wg2);
  k_prep_x<<<16384, 256, 0, stream>>>(X, Xt);
  k_gemm<<<dim3(32, 128), 256, 0, stream>>>(Xt, Ubt, biasc, xp2);
  k_zero<<<16, 256, 0, stream>>>((u32x4*)Ubt);   // after gemm: Ubt dead -> zeros
  k_rec<<<NB, 256, 0, stream>>>(Wg2, xp2, Xt, Ubt, sync);
  k_out<<<8192, 256, 0, stream>>>(Xt, out);
}